// Round 1
// baseline (53.474 us; speedup 1.0000x reference)
//
#include <hip/hip_runtime.h>
#include <math.h>

#define N_  2
#define A_  360
#define M_  512
#define NP_ 32
#define PS_ 64

// One thread = one output pixel (n, p, i, j). Loop over 360 angles.
// Block = 256 threads = a 4-row x 64-col strip of one (n,p) patch.
// Grid = N*NP*(PS/4) = 1024 blocks.
__global__ __launch_bounds__(256) void fbp_kernel(
    const float* __restrict__ sino,   // (N,1,A,M)
    const float* __restrict__ theta,  // (A)
    const float* __restrict__ cxs,    // (NP)
    const float* __restrict__ cys,    // (NP)
    float* __restrict__ out)          // (N,NP,PS,PS)
{
    __shared__ float2 trig[A_];       // {cos*half, sin*half}
    const float half = (float)(M_ - 1) * 0.5f;   // 255.5

    const int tid = threadIdx.x;

    // Fill trig table (uniform per block; redundant across blocks but trivial)
    for (int a = tid; a < A_; a += 256) {
        float th = theta[a];
        float c = cosf(th);
        float s = sinf(th);
        trig[a] = make_float2(c * half, s * half);
    }
    __syncthreads();

    const int bid  = blockIdx.x;
    const int tile = bid & 15;          // which 4-row strip
    const int p    = (bid >> 4) & (NP_ - 1);
    const int n    = bid >> 9;

    const int j = tid & (PS_ - 1);
    const int i = (tile << 2) + (tid >> 6);

    // gX = (x_i + cx)/half - 1 ; gy = (x_j + cy)/half - 1  (match ref exactly)
    const float gX = ((float)(i - PS_ / 2) + cxs[p]) / half - 1.0f;
    const float gy = ((float)(j - PS_ / 2) + cys[p]) / half - 1.0f;
    const float ngy = -gy;

    const float* __restrict__ srow = sino + n * (A_ * M_);

    float acc = 0.0f;
    #pragma unroll 4
    for (int a = 0; a < A_; ++a) {
        const float2 cs = trig[a];
        // u = ((gX*ct - gy*st) + 1) * half  ==  gX*(ct*h) + (-gy)*(st*h) + h
        const float u   = fmaf(gX, cs.x, fmaf(ngy, cs.y, half));
        const float i0f = floorf(u);
        const float w   = u - i0f;
        const int   i0  = (int)i0f;
        const int   i1  = i0 + 1;
        // w0 valid iff 0 <= i0 <= M-1 ; w1 valid iff 0 <= i1 <= M-1
        const float w0 = ((unsigned)i0 <= (unsigned)(M_ - 1)) ? (1.0f - w) : 0.0f;
        const float w1 = ((unsigned)i1 <= (unsigned)(M_ - 1)) ? w : 0.0f;
        const int c0 = min(max(i0, 0), M_ - 1);
        const int c1 = min(max(i1, 0), M_ - 1);
        const float* __restrict__ r = srow + a * M_;
        const float g0 = r[c0];
        const float g1 = r[c1];
        acc = fmaf(g0, w0, fmaf(g1, w1, acc));
    }

    const float inside = (fmaf(gX, gX, gy * gy) <= 1.0f) ? 1.0f : 0.0f;
    const float scale  = (float)(M_PI / (2.0 * (double)A_));
    out[(((n * NP_) + p) * PS_ + i) * PS_ + j] = acc * inside * scale;
}

extern "C" void kernel_launch(void* const* d_in, const int* in_sizes, int n_in,
                              void* d_out, int out_size, void* d_ws, size_t ws_size,
                              hipStream_t stream) {
    const float* sino  = (const float*)d_in[0];
    const float* theta = (const float*)d_in[1];
    const float* cxs   = (const float*)d_in[2];
    const float* cys   = (const float*)d_in[3];
    float* out = (float*)d_out;

    const int blocks = N_ * NP_ * (PS_ * PS_ / 256);  // 1024
    fbp_kernel<<<dim3(blocks), dim3(256), 0, stream>>>(sino, theta, cxs, cys, out);
}

// Round 2
// 48.587 us; speedup vs baseline: 1.1006x; 1.1006x over previous
//
#include <hip/hip_runtime.h>
#include <math.h>

#define N_  2
#define A_  360
#define M_  512
#define NP_ 32
#define PS_ 64

// unaligned-tolerant float2 (address is only 4-byte aligned)
typedef float f2u __attribute__((ext_vector_type(2), aligned(4)));

// One thread = one output pixel (n, p, i, j). Loop over 360 angles.
// Inside-mask pixels provably have u in [0,511] -> no boundary logic needed;
// a single clamp to [0, 510.999] keeps masked-out pixels' addresses safe.
__global__ __launch_bounds__(256) void fbp_kernel(
    const float* __restrict__ sino,   // (N,1,A,M)
    const float* __restrict__ theta,  // (A)
    const float* __restrict__ cxs,    // (NP)
    const float* __restrict__ cys,    // (NP)
    float* __restrict__ out)          // (N,NP,PS,PS)
{
    __shared__ float2 trig[A_];       // {cos*half, sin*half}
    const float half = 255.5f;        // (M-1)/2

    const int tid = threadIdx.x;

    for (int a = tid; a < A_; a += 256) {
        float th = theta[a];
        trig[a] = make_float2(cosf(th) * half, sinf(th) * half);
    }
    __syncthreads();

    const int bid  = blockIdx.x;
    const int tile = bid & 15;              // 4-row strip within patch
    const int p    = (bid >> 4) & (NP_ - 1);
    const int n    = bid >> 9;

    const int j = tid & (PS_ - 1);
    const int i = (tile << 2) + (tid >> 6);

    const float gX  = ((float)(i - PS_ / 2) + cxs[p]) / half - 1.0f;
    const float gy  = ((float)(j - PS_ / 2) + cys[p]) / half - 1.0f;
    const float ngy = -gy;

    const float* __restrict__ srow = sino + n * (A_ * M_);

    float accG = 0.0f;   // sum of g0
    float accW = 0.0f;   // sum of w*(g1-g0)
    #pragma unroll 8
    for (int a = 0; a < A_; ++a) {
        const float2 cs = trig[a];
        float u = fmaf(gX, cs.x, fmaf(ngy, cs.y, half));
        u = fminf(fmaxf(u, 0.0f), 510.999f);      // safety clamp (see header)
        const int   i0  = (int)u;                 // u>=0: trunc == floor
        const float w   = u - (float)i0;
        const f2u   g   = *(const f2u*)(srow + a * M_ + i0);
        accG += g.x;
        accW  = fmaf(w, g.y - g.x, accW);
    }

    const float inside = (fmaf(gX, gX, gy * gy) <= 1.0f) ? 1.0f : 0.0f;
    const float scale  = (float)(M_PI / (2.0 * (double)A_));
    out[(((n * NP_) + p) * PS_ + i) * PS_ + j] = (accG + accW) * inside * scale;
}

extern "C" void kernel_launch(void* const* d_in, const int* in_sizes, int n_in,
                              void* d_out, int out_size, void* d_ws, size_t ws_size,
                              hipStream_t stream) {
    const float* sino  = (const float*)d_in[0];
    const float* theta = (const float*)d_in[1];
    const float* cxs   = (const float*)d_in[2];
    const float* cys   = (const float*)d_in[3];
    float* out = (float*)d_out;

    const int blocks = N_ * NP_ * (PS_ * PS_ / 256);  // 1024
    fbp_kernel<<<dim3(blocks), dim3(256), 0, stream>>>(sino, theta, cxs, cys, out);
}

// Round 4
// 48.080 us; speedup vs baseline: 1.1122x; 1.0105x over previous
//
#include <hip/hip_runtime.h>
#include <math.h>

#define N_  2
#define A_  360
#define M_  512
#define NP_ 32
#define PS_ 64
#define HALF_A (A_ / 2)

// unaligned-tolerant float2 (address is only 4-byte aligned)
typedef float f2u __attribute__((ext_vector_type(2), aligned(4)));

// 512-thread blocks: two 256-thread "angle teams" share one 4-row x 64-col
// pixel strip. Team t sums angles [t*180, t*180+180); LDS-reduce at the end.
// Grid = 1024 blocks x 8 waves = exactly 4 blocks/CU = 32 waves/CU (100%).
__global__ __launch_bounds__(512) void fbp_kernel(
    const float* __restrict__ sino,   // (N,1,A,M)
    const float* __restrict__ theta,  // (A)
    const float* __restrict__ cxs,    // (NP)
    const float* __restrict__ cys,    // (NP)
    float* __restrict__ out)          // (N,NP,PS,PS)
{
    __shared__ float2 trig[A_];       // {cos*half, sin*half}
    __shared__ float  red[256];       // cross-team reduction
    const float half = 255.5f;        // (M-1)/2

    const int tid = threadIdx.x;

    for (int a = tid; a < A_; a += 512) {
        float th = theta[a];
        trig[a] = make_float2(cosf(th) * half, sinf(th) * half);
    }
    __syncthreads();

    const int team = tid >> 8;        // 0 or 1
    const int t    = tid & 255;       // pixel slot within strip

    const int bid  = blockIdx.x;
    const int tile = bid & 15;              // 4-row strip within patch
    const int p    = (bid >> 4) & (NP_ - 1);
    const int n    = bid >> 9;

    const int j = t & (PS_ - 1);
    const int i = (tile << 2) + (t >> 6);

    const float gX  = ((float)(i - PS_ / 2) + cxs[p]) / half - 1.0f;
    const float gy  = ((float)(j - PS_ / 2) + cys[p]) / half - 1.0f;
    const float ngy = -gy;

    const float* __restrict__ srow = sino + n * (A_ * M_);

    const int a0 = team * HALF_A;

    float accG = 0.0f;   // sum of g0
    float accW = 0.0f;   // sum of w*(g1-g0)
    #pragma unroll 4
    for (int a = a0; a < a0 + HALF_A; ++a) {
        const float2 cs = trig[a];
        // u = ((gX*ct - gy*st) + 1)*half ; inside-mask pixels have u in [0,511]
        float u = fmaf(gX, cs.x, fmaf(ngy, cs.y, half));
        u = fminf(fmaxf(u, 0.0f), 510.999f);      // safety clamp for masked-out px
        const int   i0  = (int)u;                 // u>=0: trunc == floor
        const float w   = __builtin_amdgcn_fractf(u);
        const f2u   g   = *(const f2u*)(srow + a * M_ + i0);
        accG += g.x;
        accW  = fmaf(w, g.y - g.x, accW);
    }

    const float part = accG + accW;
    if (team == 1) red[t] = part;
    __syncthreads();
    if (team == 0) {
        const float inside = (fmaf(gX, gX, gy * gy) <= 1.0f) ? 1.0f : 0.0f;
        const float scale  = (float)(M_PI / (2.0 * (double)A_));
        out[(((n * NP_) + p) * PS_ + i) * PS_ + j] =
            (part + red[t]) * inside * scale;
    }
}

extern "C" void kernel_launch(void* const* d_in, const int* in_sizes, int n_in,
                              void* d_out, int out_size, void* d_ws, size_t ws_size,
                              hipStream_t stream) {
    const float* sino  = (const float*)d_in[0];
    const float* theta = (const float*)d_in[1];
    const float* cxs   = (const float*)d_in[2];
    const float* cys   = (const float*)d_in[3];
    float* out = (float*)d_out;

    const int blocks = N_ * NP_ * (PS_ * PS_ / 256);  // 1024
    fbp_kernel<<<dim3(blocks), dim3(512), 0, stream>>>(sino, theta, cxs, cys, out);
}